// Round 20
// baseline (376.639 us; speedup 1.0000x reference)
//
#include <hip/hip_runtime.h>

// ---------------------------------------------------------------------------
// HedgeHog attention distillation map: pred = (fq.fk^T) rownorm, true = softmax(q0.k0^T/8)
// Output [2,2,16,2048,2048] fp32 = 1.07 GiB -> HBM-write-bound.
//
// v20 = v19 (wide-slab 1KB-run wave-private writer, 367us) + ONE lever:
// obuf fp32 -> bf16 (8KB/wave) => 8 waves/block fit in exactly 160KB LDS
// (fkS 64 + k0S 32 + 8x8). 2 waves/SIMD doubles store concurrency and
// latency hiding. Store path: ushort4 LDS read -> f32x4 convert -> 1KB run.
// Run-length ladder so far: 64B->1.2, 512B->2.5, 1KB->3.6 TB/s.
// ---------------------------------------------------------------------------

typedef __attribute__((ext_vector_type(8))) short  bf16x8;
typedef __attribute__((ext_vector_type(4))) float  f32x4;
typedef __attribute__((ext_vector_type(4))) unsigned short u16x4;

#define NN 2048
#define NBH 32

__device__ float g_part[NBH * 8 * 128];   // fk colsum partials
__device__ float g_normP[NBH * NN];       // 1 / pred row sum
__device__ float g_normT[NBH * NN];       // 1 / true row sum

__device__ __forceinline__ float bf2f(unsigned short u) {
  union { unsigned int i; float f; } v; v.i = ((unsigned int)u) << 16; return v.f;
}
__device__ __forceinline__ unsigned short f2bf(float f) {
  union { float f; unsigned int i; } v; v.f = f;
  unsigned int x = v.i;
  return (unsigned short)((x + 0x7FFFu + ((x >> 16) & 1u)) >> 16);  // RNE
}
__device__ __forceinline__ bf16x8 cvt8(const float* __restrict__ p) {
  bf16x8 v;
#pragma unroll
  for (int i = 0; i < 8; i++) v[i] = (short)f2bf(p[i]);
  return v;
}
__device__ __forceinline__ f32x4 mfma16(bf16x8 a, bf16x8 b, f32x4 c) {
  return __builtin_amdgcn_mfma_f32_16x16x32_bf16(a, b, c, 0, 0, 0);
}

// ---------------------------------------------------------------------------
// Kernel 1: projections + hedgehog features. One wave owns 16 rows.
// ---------------------------------------------------------------------------
__device__ __forceinline__ void proj_chain(
    const bf16x8 ax[2],
    const float* __restrict__ W1, const float* __restrict__ b1,
    const float* __restrict__ W2, const float* __restrict__ b2,
    unsigned short* __restrict__ o1w, unsigned short* __restrict__ o2w,
    unsigned short (*Tq)[72], unsigned short (*Tf)[136],
    long r0, int l15, int g, int l)
{
#pragma unroll
  for (int nt = 0; nt < 4; nt++) {
    f32x4 acc = {0.f, 0.f, 0.f, 0.f};
    acc = mfma16(ax[0], cvt8(W1 + (nt * 16 + l15) * 64 + g * 8), acc);
    acc = mfma16(ax[1], cvt8(W1 + (nt * 16 + l15) * 64 + 32 + g * 8), acc);
    float bv = b1[nt * 16 + l15];
#pragma unroll
    for (int j = 0; j < 4; j++)
      Tq[g * 4 + j][nt * 16 + l15] = f2bf(acc[j] + bv);   // C layout: row=(l>>4)*4+j, col=l&15
  }
#pragma unroll
  for (int i = 0; i < 2; i++) {
    int c = i * 64 + l;
    int r = c >> 3, cc = c & 7;
    *(bf16x8*)(o1w + (r0 + r) * 64 + cc * 8) = *(const bf16x8*)&Tq[r][cc * 8];
  }
  bf16x8 a1[2];
#pragma unroll
  for (int kk = 0; kk < 2; kk++)
    a1[kk] = *(const bf16x8*)&Tq[l15][kk * 32 + g * 8];
#pragma unroll
  for (int nt = 0; nt < 4; nt++) {
    f32x4 acc = {0.f, 0.f, 0.f, 0.f};
    acc = mfma16(a1[0], cvt8(W2 + (nt * 16 + l15) * 64 + g * 8), acc);
    acc = mfma16(a1[1], cvt8(W2 + (nt * 16 + l15) * 64 + 32 + g * 8), acc);
    float bv = b2[nt * 16 + l15];
#pragma unroll
    for (int j = 0; j < 4; j++) {
      float h = acc[j] + bv;
      Tf[g * 4 + j][nt * 16 + l15]      = f2bf(__expf(h));
      Tf[g * 4 + j][64 + nt * 16 + l15] = f2bf(__expf(-h));
    }
  }
#pragma unroll
  for (int i = 0; i < 4; i++) {
    int c = i * 64 + l;
    int r = c >> 4, cc = c & 15;
    *(bf16x8*)(o2w + (r0 + r) * 128 + cc * 8) = *(const bf16x8*)&Tf[r][cc * 8];
  }
}

__global__ __launch_bounds__(256) void k_proj(
    const float* __restrict__ x,
    const float* __restrict__ Wq,  const float* __restrict__ bq,
    const float* __restrict__ Wk,  const float* __restrict__ bk,
    const float* __restrict__ Wmq, const float* __restrict__ bmq,
    const float* __restrict__ Wmk, const float* __restrict__ bmk,
    unsigned short* __restrict__ q0w, unsigned short* __restrict__ k0w,
    unsigned short* __restrict__ fqw, unsigned short* __restrict__ fkw)
{
  const int tid = threadIdx.x;
  const int w = tid >> 6, l = tid & 63;
  const int l15 = l & 15, g = l >> 4;
  const long r0 = ((long)blockIdx.x * 4 + w) * 16;

  __shared__ unsigned short TqS[4][16][72];
  __shared__ unsigned short TfS[4][16][136];

  bf16x8 ax[2];
#pragma unroll
  for (int kk = 0; kk < 2; kk++)
    ax[kk] = cvt8(x + (r0 + l15) * 64 + kk * 32 + g * 8);

  proj_chain(ax, Wq, bq, Wmq, bmq, q0w, fqw, TqS[w], TfS[w], r0, l15, g, l);
  proj_chain(ax, Wk, bk, Wmk, bmk, k0w, fkw, TqS[w], TfS[w], r0, l15, g, l);
}

// ---------------------------------------------------------------------------
// Kernel 2: fk column-sum partials (bh, part): rows part*256..+255.
// ---------------------------------------------------------------------------
__global__ __launch_bounds__(256) void k_colsum1(const unsigned short* __restrict__ fkw)
{
  const int bh = blockIdx.x, part = blockIdx.y;
  const int tid = threadIdx.x;
  const int cg = tid & 15, rg = tid >> 4;
  const unsigned short* fkp = fkw + ((long)bh * NN + part * 256 + rg * 16) * 128 + cg * 8;

  float a8[8] = {0.f, 0.f, 0.f, 0.f, 0.f, 0.f, 0.f, 0.f};
#pragma unroll
  for (int r = 0; r < 16; r++) {
    bf16x8 v = *(const bf16x8*)(fkp + (long)r * 128);
#pragma unroll
    for (int j = 0; j < 8; j++) a8[j] += bf2f((unsigned short)v[j]);
  }
  __shared__ float red[16][132];
#pragma unroll
  for (int j = 0; j < 8; j++) red[rg][cg * 8 + j] = a8[j];
  __syncthreads();
  if (tid < 128) {
    float s = 0.f;
#pragma unroll
    for (int r = 0; r < 16; r++) s += red[r][tid];
    g_part[(bh * 8 + part) * 128 + tid] = s;
  }
}

// ---------------------------------------------------------------------------
// Kernel 3a: pred normalizers (factorized dot with fk colsums).
// ---------------------------------------------------------------------------
__global__ __launch_bounds__(256) void k_normP(const unsigned short* __restrict__ fqw)
{
  const int bh = blockIdx.x, rg = blockIdx.y;   // (32, 16)
  const int tid = threadIdx.x;

  __shared__ float sfk[128];
  if (tid < 128) {
    float s = 0.f;
#pragma unroll
    for (int pt = 0; pt < 8; pt++) s += g_part[bh * 1024 + pt * 128 + tid];
    sfk[tid] = s;
  }
  __syncthreads();
  if (tid < 128) {
    const int row = rg * 128 + tid;
    const unsigned short* p = fqw + ((long)bh * NN + row) * 128;
    float d = 0.f;
#pragma unroll
    for (int i = 0; i < 16; i++) {
      bf16x8 v = *(const bf16x8*)(p + i * 8);
#pragma unroll
      for (int jj = 0; jj < 8; jj++) d += bf2f((unsigned short)v[jj]) * sfk[i * 8 + jj];
    }
    g_normP[bh * NN + row] = 1.0f / d;
  }
}

// ---------------------------------------------------------------------------
// Kernel 3b: true normalizers. Grid (32, 64): 32 rows/block.
// ---------------------------------------------------------------------------
__global__ __launch_bounds__(256) void k_normT(
    const unsigned short* __restrict__ q0w, const unsigned short* __restrict__ k0w)
{
  const int bh = blockIdx.x, rb = blockIdx.y * 32;
  const int tid = threadIdx.x;
  const int w = tid >> 6, l = tid & 63;
  const int l15 = l & 15, g = l >> 4;

  __shared__ float sred[2][4][16];
  const unsigned short* k0p = k0w + (long)bh * NN * 64;

#pragma unroll
  for (int tt = 0; tt < 2; tt++) {
    const unsigned short* qp = q0w + ((long)bh * NN + rb + tt * 16) * 64;
    bf16x8 a0 = *(const bf16x8*)(qp + l15 * 64 + g * 8);
    bf16x8 a1 = *(const bf16x8*)(qp + l15 * 64 + 32 + g * 8);
    float st[4] = {0.f, 0.f, 0.f, 0.f};
    for (int kt = w; kt < 128; kt += 4) {
      const unsigned short* bp = k0p + (long)(kt * 16 + l15) * 64 + g * 8;
      f32x4 acc = {0.f, 0.f, 0.f, 0.f};
      acc = mfma16(a0, *(const bf16x8*)bp, acc);
      acc = mfma16(a1, *(const bf16x8*)(bp + 32), acc);
#pragma unroll
      for (int j = 0; j < 4; j++) st[j] += __expf(acc[j] * 0.125f);
    }
#pragma unroll
    for (int j = 0; j < 4; j++) {
      float v = st[j];
      v += __shfl_xor(v, 1, 16);
      v += __shfl_xor(v, 2, 16);
      v += __shfl_xor(v, 4, 16);
      v += __shfl_xor(v, 8, 16);
      if (l15 == 0) sred[tt][w][g * 4 + j] = v;
    }
  }
  __syncthreads();
  if (tid < 32) {
    const int t2 = tid >> 4, rr = tid & 15;
    float s = sred[t2][0][rr] + sred[t2][1][rr] + sred[t2][2][rr] + sred[t2][3][rr];
    g_normT[bh * NN + rb + t2 * 16 + rr] = 1.0f / s;
  }
}

// ---------------------------------------------------------------------------
// Kernel 4: wide-slab wave-private writer, 8 waves (bf16 obuf). Block =
// (bh, 256-key slab), 512 threads, 1 block/CU, 256 blocks (one round).
// XOR-swizzled unpadded operand tiles; each wave sweeps rgs w, w+8, ...
// barrier-free; store instr = one full 1KB-contiguous row (bf16->fp32 cvt).
// ---------------------------------------------------------------------------
__global__ __launch_bounds__(512, 1) void k_write(
    const unsigned short* __restrict__ q0w, const unsigned short* __restrict__ k0w,
    const unsigned short* __restrict__ fqw, const unsigned short* __restrict__ fkw,
    float* __restrict__ out)
{
  const int bh = blockIdx.x;          // 0..31
  const int slab = blockIdx.y;        // 0..7 (256-key slab)
  const int tid = threadIdx.x;
  const int w = tid >> 6, l = tid & 63;
  const int l15 = l & 15, g = l >> 4;

  // exactly 160 KB: 65536 + 32768 + 65536
  __shared__ unsigned short fkS[256 * 128];   // XOR-swz: granule ^= row&15
  __shared__ unsigned short k0S[256 * 64];    // XOR-swz: granule ^= row&7
  __shared__ unsigned short obuf[8][16][256]; // wave-private 16x256 bf16 plane

  const unsigned short* fkp = fkw + ((long)bh * NN + slab * 256) * 128;
  const unsigned short* k0p = k0w + ((long)bh * NN + slab * 256) * 64;
  const unsigned short* fqb = fqw + (long)bh * NN * 128;
  const unsigned short* q0b = q0w + (long)bh * NN * 64;
  const float* npb = g_normP + bh * NN;
  const float* ntb = g_normT + bh * NN;
  const long ob_p = (long)bh * NN * NN + slab * 256;
  const long ob_t = ob_p + (long)NBH * NN * NN;

  // ---- stage slab operands once, XOR-swizzled (512 threads) ----
#pragma unroll
  for (int i = 0; i < 8; i++) {
    int c = i * 512 + tid;            // granule id 0..4095
    int r = c >> 4, gr = c & 15;      // row, granule-in-row
    *(bf16x8*)&fkS[r * 128 + (gr ^ (r & 15)) * 8] =
        *(const bf16x8*)(fkp + (long)r * 128 + gr * 8);
  }
#pragma unroll
  for (int i = 0; i < 4; i++) {
    int c = i * 512 + tid;            // granule id 0..2047
    int r = c >> 3, gr = c & 7;
    *(bf16x8*)&k0S[r * 64 + (gr ^ (r & 7)) * 8] =
        *(const bf16x8*)(k0p + (long)r * 64 + gr * 8);
  }
  __syncthreads();

  unsigned short (* const obufW)[256] = obuf[w];

  // ---- A-frag register sets (depth-1 double buffer, wave-local) ----
  bf16x8 aqA[4], aqB[4], akA[2], akB[2];
  f32x4 ipA, ipB, itA, itB;

#define PF(I, AQ, AK, IP, IT) {                                                \
    if ((I) < 16) {                                                            \
      const int qr_ = (w + (I) * 8) * 16;                                      \
      _Pragma("unroll")                                                        \
      for (int kk = 0; kk < 4; kk++)                                           \
        AQ[kk] = *(const bf16x8*)(fqb + (long)(qr_ + l15) * 128 + kk * 32 + g * 8); \
      _Pragma("unroll")                                                        \
      for (int kk = 0; kk < 2; kk++)                                           \
        AK[kk] = *(const bf16x8*)(q0b + (long)(qr_ + l15) * 64 + kk * 32 + g * 8);  \
      IP = *(const f32x4*)(npb + qr_ + g * 4);                                 \
      IT = *(const f32x4*)(ntb + qr_ + g * 4);                                 \
    }                                                                          \
  }

  // pred: 16 key-tiles; fkS granule (kk*4+g) ^ l15 of row key
#define CPRED(AQ, IP) {                                                        \
    _Pragma("unroll")                                                          \
    for (int t = 0; t < 16; t++) {                                             \
      const int key = t * 16 + l15;                                            \
      f32x4 acc = {0.f, 0.f, 0.f, 0.f};                                        \
      _Pragma("unroll")                                                        \
      for (int kk = 0; kk < 4; kk++)                                           \
        acc = mfma16(AQ[kk],                                                   \
              *(const bf16x8*)&fkS[key * 128 + ((kk * 4 + g) ^ l15) * 8], acc);\
      _Pragma("unroll")                                                        \
      for (int j = 0; j < 4; j++)                                              \
        obufW[g * 4 + j][key] = f2bf(acc[j] * IP[j]);                          \
    }                                                                          \
  }

#define CTRUE(AK, IT) {                                                        \
    _Pragma("unroll")                                                          \
    for (int t = 0; t < 16; t++) {                                             \
      const int key = t * 16 + l15;                                            \
      f32x4 acc = {0.f, 0.f, 0.f, 0.f};                                        \
      _Pragma("unroll")                                                        \
      for (int kk = 0; kk < 2; kk++)                                           \
        acc = mfma16(AK[kk],                                                   \
              *(const bf16x8*)&k0S[key * 64 + ((kk * 4 + g) ^ (l15 & 7)) * 8], acc); \
      _Pragma("unroll")                                                        \
      for (int j = 0; j < 4; j++)                                              \
        obufW[g * 4 + j][key] = f2bf(__expf(acc[j] * 0.125f) * IT[j]);         \
    }                                                                          \
  }

  // store the wave's 16x256 plane: 16 rows, each one 1KB-contiguous run
#define STOREW(PL, I) {                                                        \
    const long ob = ((PL) ? ob_t : ob_p) + (long)((w + (I) * 8) * 16) * NN;    \
    _Pragma("unroll")                                                          \
    for (int r = 0; r < 16; r++) {                                             \
      u16x4 hv = *(const u16x4*)&obufW[r][l * 4];                              \
      f32x4 v;                                                                 \
      _Pragma("unroll")                                                        \
      for (int j = 0; j < 4; j++) v[j] = bf2f(hv[j]);                          \
      *(f32x4*)(out + ob + (long)r * NN + l * 4) = v;                          \
    }                                                                          \
  }

#define BODY(I, AQ, AK, IP, IT, PAQ, PAK, PIP, PIT) {                          \
    PF((I) + 1, PAQ, PAK, PIP, PIT);                                           \
    CPRED(AQ, IP);                                                             \
    asm volatile("s_waitcnt lgkmcnt(0)" ::: "memory");                         \
    STOREW(0, I);                                                              \
    asm volatile("s_waitcnt lgkmcnt(0)" ::: "memory");                         \
    CTRUE(AK, IT);                                                             \
    asm volatile("s_waitcnt lgkmcnt(0)" ::: "memory");                         \
    STOREW(1, I);                                                              \
    asm volatile("s_waitcnt lgkmcnt(0)" ::: "memory");                         \
  }

  PF(0, aqA, akA, ipA, itA);

#pragma unroll 1
  for (int i2 = 0; i2 < 8; i2++) {
    BODY(2 * i2,     aqA, akA, ipA, itA, aqB, akB, ipB, itB);
    BODY(2 * i2 + 1, aqB, akB, ipB, itB, aqA, akA, ipA, itA);
  }

#undef PF
#undef CPRED
#undef CTRUE
#undef STOREW
#undef BODY
}

extern "C" void kernel_launch(void* const* d_in, const int* in_sizes, int n_in,
                              void* d_out, int out_size, void* d_ws, size_t ws_size,
                              hipStream_t stream) {
  const float* x   = (const float*)d_in[0];
  const float* Wq  = (const float*)d_in[1];
  const float* bq  = (const float*)d_in[2];
  const float* Wk  = (const float*)d_in[3];
  const float* bk  = (const float*)d_in[4];
  const float* Wmq = (const float*)d_in[5];
  const float* bmq = (const float*)d_in[6];
  const float* Wmk = (const float*)d_in[7];
  const float* bmk = (const float*)d_in[8];
  float* out = (float*)d_out;

  // ws layout (bf16): q0[32][2048][64], k0[...], fq[32][2048][128], fk[...] = 48 MB
  unsigned short* q0w = (unsigned short*)d_ws;
  unsigned short* k0w = q0w + (long)NBH * NN * 64;
  unsigned short* fqw = k0w + (long)NBH * NN * 64;
  unsigned short* fkw = fqw + (long)NBH * NN * 128;

  hipLaunchKernelGGL(k_proj, dim3(1024), dim3(256), 0, stream,
                     x, Wq, bq, Wk, bk, Wmq, bmq, Wmk, bmk, q0w, k0w, fqw, fkw);
  hipLaunchKernelGGL(k_colsum1, dim3(NBH, 8), dim3(256), 0, stream, fkw);
  hipLaunchKernelGGL(k_normP, dim3(NBH, 16), dim3(256), 0, stream, fqw);
  hipLaunchKernelGGL(k_normT, dim3(NBH, 64), dim3(256), 0, stream, q0w, k0w);
  hipLaunchKernelGGL(k_write, dim3(NBH, 8), dim3(512), 0, stream,
                     q0w, k0w, fqw, fkw, out);
}

// Round 21
// 355.555 us; speedup vs baseline: 1.0593x; 1.0593x over previous
//
#include <hip/hip_runtime.h>

// ---------------------------------------------------------------------------
// HedgeHog attention distillation map: pred = (fq.fk^T) rownorm, true = softmax(q0.k0^T/8)
// Output [2,2,16,2048,2048] fp32 = 1.07 GiB -> HBM-write-bound.
//
// v21 = v19 (best, 367us: wide-slab 1KB-run wave-private writer) + store-path
// levers only: (1) nontemporal stores (bypass L2 dirty-eviction arbitration;
// safe now that every store is a full-line-aligned 1KB run -- v6's +20%
// amplification was scattered 512B segments), (2) STOREW batches all 16
// ds_reads into regs then issues 16 back-to-back stores (16KB uninterrupted
// burst per wave). Everything else byte-identical to v19.
// Run-length ladder: 64B->1.2, 512B->2.5, 1KB->3.6 TB/s; v20 (2x waves) null.
// ---------------------------------------------------------------------------

typedef __attribute__((ext_vector_type(8))) short  bf16x8;
typedef __attribute__((ext_vector_type(4))) float  f32x4;

#define NN 2048
#define NBH 32

__device__ float g_part[NBH * 8 * 128];   // fk colsum partials
__device__ float g_normP[NBH * NN];       // 1 / pred row sum
__device__ float g_normT[NBH * NN];       // 1 / true row sum

__device__ __forceinline__ float bf2f(unsigned short u) {
  union { unsigned int i; float f; } v; v.i = ((unsigned int)u) << 16; return v.f;
}
__device__ __forceinline__ unsigned short f2bf(float f) {
  union { float f; unsigned int i; } v; v.f = f;
  unsigned int x = v.i;
  return (unsigned short)((x + 0x7FFFu + ((x >> 16) & 1u)) >> 16);  // RNE
}
__device__ __forceinline__ bf16x8 cvt8(const float* __restrict__ p) {
  bf16x8 v;
#pragma unroll
  for (int i = 0; i < 8; i++) v[i] = (short)f2bf(p[i]);
  return v;
}
__device__ __forceinline__ f32x4 mfma16(bf16x8 a, bf16x8 b, f32x4 c) {
  return __builtin_amdgcn_mfma_f32_16x16x32_bf16(a, b, c, 0, 0, 0);
}

// ---------------------------------------------------------------------------
// Kernel 1: projections + hedgehog features. One wave owns 16 rows.
// ---------------------------------------------------------------------------
__device__ __forceinline__ void proj_chain(
    const bf16x8 ax[2],
    const float* __restrict__ W1, const float* __restrict__ b1,
    const float* __restrict__ W2, const float* __restrict__ b2,
    unsigned short* __restrict__ o1w, unsigned short* __restrict__ o2w,
    unsigned short (*Tq)[72], unsigned short (*Tf)[136],
    long r0, int l15, int g, int l)
{
#pragma unroll
  for (int nt = 0; nt < 4; nt++) {
    f32x4 acc = {0.f, 0.f, 0.f, 0.f};
    acc = mfma16(ax[0], cvt8(W1 + (nt * 16 + l15) * 64 + g * 8), acc);
    acc = mfma16(ax[1], cvt8(W1 + (nt * 16 + l15) * 64 + 32 + g * 8), acc);
    float bv = b1[nt * 16 + l15];
#pragma unroll
    for (int j = 0; j < 4; j++)
      Tq[g * 4 + j][nt * 16 + l15] = f2bf(acc[j] + bv);   // C layout: row=(l>>4)*4+j, col=l&15
  }
#pragma unroll
  for (int i = 0; i < 2; i++) {
    int c = i * 64 + l;
    int r = c >> 3, cc = c & 7;
    *(bf16x8*)(o1w + (r0 + r) * 64 + cc * 8) = *(const bf16x8*)&Tq[r][cc * 8];
  }
  bf16x8 a1[2];
#pragma unroll
  for (int kk = 0; kk < 2; kk++)
    a1[kk] = *(const bf16x8*)&Tq[l15][kk * 32 + g * 8];
#pragma unroll
  for (int nt = 0; nt < 4; nt++) {
    f32x4 acc = {0.f, 0.f, 0.f, 0.f};
    acc = mfma16(a1[0], cvt8(W2 + (nt * 16 + l15) * 64 + g * 8), acc);
    acc = mfma16(a1[1], cvt8(W2 + (nt * 16 + l15) * 64 + 32 + g * 8), acc);
    float bv = b2[nt * 16 + l15];
#pragma unroll
    for (int j = 0; j < 4; j++) {
      float h = acc[j] + bv;
      Tf[g * 4 + j][nt * 16 + l15]      = f2bf(__expf(h));
      Tf[g * 4 + j][64 + nt * 16 + l15] = f2bf(__expf(-h));
    }
  }
#pragma unroll
  for (int i = 0; i < 4; i++) {
    int c = i * 64 + l;
    int r = c >> 4, cc = c & 15;
    *(bf16x8*)(o2w + (r0 + r) * 128 + cc * 8) = *(const bf16x8*)&Tf[r][cc * 8];
  }
}

__global__ __launch_bounds__(256) void k_proj(
    const float* __restrict__ x,
    const float* __restrict__ Wq,  const float* __restrict__ bq,
    const float* __restrict__ Wk,  const float* __restrict__ bk,
    const float* __restrict__ Wmq, const float* __restrict__ bmq,
    const float* __restrict__ Wmk, const float* __restrict__ bmk,
    unsigned short* __restrict__ q0w, unsigned short* __restrict__ k0w,
    unsigned short* __restrict__ fqw, unsigned short* __restrict__ fkw)
{
  const int tid = threadIdx.x;
  const int w = tid >> 6, l = tid & 63;
  const int l15 = l & 15, g = l >> 4;
  const long r0 = ((long)blockIdx.x * 4 + w) * 16;

  __shared__ unsigned short TqS[4][16][72];
  __shared__ unsigned short TfS[4][16][136];

  bf16x8 ax[2];
#pragma unroll
  for (int kk = 0; kk < 2; kk++)
    ax[kk] = cvt8(x + (r0 + l15) * 64 + kk * 32 + g * 8);

  proj_chain(ax, Wq, bq, Wmq, bmq, q0w, fqw, TqS[w], TfS[w], r0, l15, g, l);
  proj_chain(ax, Wk, bk, Wmk, bmk, k0w, fkw, TqS[w], TfS[w], r0, l15, g, l);
}

// ---------------------------------------------------------------------------
// Kernel 2: fk column-sum partials (bh, part): rows part*256..+255.
// ---------------------------------------------------------------------------
__global__ __launch_bounds__(256) void k_colsum1(const unsigned short* __restrict__ fkw)
{
  const int bh = blockIdx.x, part = blockIdx.y;
  const int tid = threadIdx.x;
  const int cg = tid & 15, rg = tid >> 4;
  const unsigned short* fkp = fkw + ((long)bh * NN + part * 256 + rg * 16) * 128 + cg * 8;

  float a8[8] = {0.f, 0.f, 0.f, 0.f, 0.f, 0.f, 0.f, 0.f};
#pragma unroll
  for (int r = 0; r < 16; r++) {
    bf16x8 v = *(const bf16x8*)(fkp + (long)r * 128);
#pragma unroll
    for (int j = 0; j < 8; j++) a8[j] += bf2f((unsigned short)v[j]);
  }
  __shared__ float red[16][132];
#pragma unroll
  for (int j = 0; j < 8; j++) red[rg][cg * 8 + j] = a8[j];
  __syncthreads();
  if (tid < 128) {
    float s = 0.f;
#pragma unroll
    for (int r = 0; r < 16; r++) s += red[r][tid];
    g_part[(bh * 8 + part) * 128 + tid] = s;
  }
}

// ---------------------------------------------------------------------------
// Kernel 3a: pred normalizers (factorized dot with fk colsums).
// ---------------------------------------------------------------------------
__global__ __launch_bounds__(256) void k_normP(const unsigned short* __restrict__ fqw)
{
  const int bh = blockIdx.x, rg = blockIdx.y;   // (32, 16)
  const int tid = threadIdx.x;

  __shared__ float sfk[128];
  if (tid < 128) {
    float s = 0.f;
#pragma unroll
    for (int pt = 0; pt < 8; pt++) s += g_part[bh * 1024 + pt * 128 + tid];
    sfk[tid] = s;
  }
  __syncthreads();
  if (tid < 128) {
    const int row = rg * 128 + tid;
    const unsigned short* p = fqw + ((long)bh * NN + row) * 128;
    float d = 0.f;
#pragma unroll
    for (int i = 0; i < 16; i++) {
      bf16x8 v = *(const bf16x8*)(p + i * 8);
#pragma unroll
      for (int jj = 0; jj < 8; jj++) d += bf2f((unsigned short)v[jj]) * sfk[i * 8 + jj];
    }
    g_normP[bh * NN + row] = 1.0f / d;
  }
}

// ---------------------------------------------------------------------------
// Kernel 3b: true normalizers. Grid (32, 64): 32 rows/block.
// ---------------------------------------------------------------------------
__global__ __launch_bounds__(256) void k_normT(
    const unsigned short* __restrict__ q0w, const unsigned short* __restrict__ k0w)
{
  const int bh = blockIdx.x, rb = blockIdx.y * 32;
  const int tid = threadIdx.x;
  const int w = tid >> 6, l = tid & 63;
  const int l15 = l & 15, g = l >> 4;

  __shared__ float sred[2][4][16];
  const unsigned short* k0p = k0w + (long)bh * NN * 64;

#pragma unroll
  for (int tt = 0; tt < 2; tt++) {
    const unsigned short* qp = q0w + ((long)bh * NN + rb + tt * 16) * 64;
    bf16x8 a0 = *(const bf16x8*)(qp + l15 * 64 + g * 8);
    bf16x8 a1 = *(const bf16x8*)(qp + l15 * 64 + 32 + g * 8);
    float st[4] = {0.f, 0.f, 0.f, 0.f};
    for (int kt = w; kt < 128; kt += 4) {
      const unsigned short* bp = k0p + (long)(kt * 16 + l15) * 64 + g * 8;
      f32x4 acc = {0.f, 0.f, 0.f, 0.f};
      acc = mfma16(a0, *(const bf16x8*)bp, acc);
      acc = mfma16(a1, *(const bf16x8*)(bp + 32), acc);
#pragma unroll
      for (int j = 0; j < 4; j++) st[j] += __expf(acc[j] * 0.125f);
    }
#pragma unroll
    for (int j = 0; j < 4; j++) {
      float v = st[j];
      v += __shfl_xor(v, 1, 16);
      v += __shfl_xor(v, 2, 16);
      v += __shfl_xor(v, 4, 16);
      v += __shfl_xor(v, 8, 16);
      if (l15 == 0) sred[tt][w][g * 4 + j] = v;
    }
  }
  __syncthreads();
  if (tid < 32) {
    const int t2 = tid >> 4, rr = tid & 15;
    float s = sred[t2][0][rr] + sred[t2][1][rr] + sred[t2][2][rr] + sred[t2][3][rr];
    g_normT[bh * NN + rb + t2 * 16 + rr] = 1.0f / s;
  }
}

// ---------------------------------------------------------------------------
// Kernel 4: wide-slab wave-private writer (v19) + nt burst stores. Block =
// (bh, 256-key slab), 4 waves, 1 block/CU, 256 blocks. XOR-swizzled unpadded
// operand tiles; wave sweeps rgs w, w+4, ... barrier-free; STOREW: 16
// ds_reads into regs, then 16 back-to-back 1KB nontemporal stores.
// ---------------------------------------------------------------------------
__global__ __launch_bounds__(256, 1) void k_write(
    const unsigned short* __restrict__ q0w, const unsigned short* __restrict__ k0w,
    const unsigned short* __restrict__ fqw, const unsigned short* __restrict__ fkw,
    float* __restrict__ out)
{
  const int bh = blockIdx.x;          // 0..31
  const int slab = blockIdx.y;        // 0..7 (256-key slab)
  const int tid = threadIdx.x;
  const int w = tid >> 6, l = tid & 63;
  const int l15 = l & 15, g = l >> 4;

  // exactly 160 KB: 65536 + 32768 + 65536
  __shared__ unsigned short fkS[256 * 128];   // XOR-swz: granule ^= row&15
  __shared__ unsigned short k0S[256 * 64];    // XOR-swz: granule ^= row&7
  __shared__ float obuf[4][16][256];          // wave-private 16x256 plane

  const unsigned short* fkp = fkw + ((long)bh * NN + slab * 256) * 128;
  const unsigned short* k0p = k0w + ((long)bh * NN + slab * 256) * 64;
  const unsigned short* fqb = fqw + (long)bh * NN * 128;
  const unsigned short* q0b = q0w + (long)bh * NN * 64;
  const float* npb = g_normP + bh * NN;
  const float* ntb = g_normT + bh * NN;
  const long ob_p = (long)bh * NN * NN + slab * 256;
  const long ob_t = ob_p + (long)NBH * NN * NN;

  // ---- stage slab operands once, XOR-swizzled (256 threads) ----
#pragma unroll
  for (int i = 0; i < 16; i++) {
    int c = i * 256 + tid;            // granule id 0..4095
    int r = c >> 4, gr = c & 15;      // row, granule-in-row
    *(bf16x8*)&fkS[r * 128 + (gr ^ (r & 15)) * 8] =
        *(const bf16x8*)(fkp + (long)r * 128 + gr * 8);
  }
#pragma unroll
  for (int i = 0; i < 8; i++) {
    int c = i * 256 + tid;            // granule id 0..2047
    int r = c >> 3, gr = c & 7;
    *(bf16x8*)&k0S[r * 64 + (gr ^ (r & 7)) * 8] =
        *(const bf16x8*)(k0p + (long)r * 64 + gr * 8);
  }
  __syncthreads();

  float (* const obufW)[256] = obuf[w];

  // ---- A-frag register sets (depth-1 double buffer, wave-local) ----
  bf16x8 aqA[4], aqB[4], akA[2], akB[2];
  f32x4 ipA, ipB, itA, itB;

#define PF(I, AQ, AK, IP, IT) {                                                \
    if ((I) < 32) {                                                            \
      const int qr_ = (w + (I) * 4) * 16;                                      \
      _Pragma("unroll")                                                        \
      for (int kk = 0; kk < 4; kk++)                                           \
        AQ[kk] = *(const bf16x8*)(fqb + (long)(qr_ + l15) * 128 + kk * 32 + g * 8); \
      _Pragma("unroll")                                                        \
      for (int kk = 0; kk < 2; kk++)                                           \
        AK[kk] = *(const bf16x8*)(q0b + (long)(qr_ + l15) * 64 + kk * 32 + g * 8);  \
      IP = *(const f32x4*)(npb + qr_ + g * 4);                                 \
      IT = *(const f32x4*)(ntb + qr_ + g * 4);                                 \
    }                                                                          \
  }

  // pred: 16 key-tiles; fkS granule (kk*4+g) ^ l15 of row key
#define CPRED(AQ, IP) {                                                        \
    _Pragma("unroll")                                                          \
    for (int t = 0; t < 16; t++) {                                             \
      const int key = t * 16 + l15;                                            \
      f32x4 acc = {0.f, 0.f, 0.f, 0.f};                                        \
      _Pragma("unroll")                                                        \
      for (int kk = 0; kk < 4; kk++)                                           \
        acc = mfma16(AQ[kk],                                                   \
              *(const bf16x8*)&fkS[key * 128 + ((kk * 4 + g) ^ l15) * 8], acc);\
      _Pragma("unroll")                                                        \
      for (int j = 0; j < 4; j++)                                              \
        obufW[g * 4 + j][key] = acc[j] * IP[j];                                \
    }                                                                          \
  }

#define CTRUE(AK, IT) {                                                        \
    _Pragma("unroll")                                                          \
    for (int t = 0; t < 16; t++) {                                             \
      const int key = t * 16 + l15;                                            \
      f32x4 acc = {0.f, 0.f, 0.f, 0.f};                                        \
      _Pragma("unroll")                                                        \
      for (int kk = 0; kk < 2; kk++)                                           \
        acc = mfma16(AK[kk],                                                   \
              *(const bf16x8*)&k0S[key * 64 + ((kk * 4 + g) ^ (l15 & 7)) * 8], acc); \
      _Pragma("unroll")                                                        \
      for (int j = 0; j < 4; j++)                                              \
        obufW[g * 4 + j][key] = __expf(acc[j] * 0.125f) * IT[j];               \
    }                                                                          \
  }

  // store the wave's 16x256 plane: batch 16 ds_reads, then 16 nt 1KB stores
#define STOREW(PL, I) {                                                        \
    const long ob = ((PL) ? ob_t : ob_p) + (long)((w + (I) * 4) * 16) * NN;    \
    f32x4 vv[16];                                                              \
    _Pragma("unroll")                                                          \
    for (int r = 0; r < 16; r++) vv[r] = *(const f32x4*)&obufW[r][l * 4];      \
    asm volatile("s_waitcnt lgkmcnt(0)" ::: "memory");                         \
    _Pragma("unroll")                                                          \
    for (int r = 0; r < 16; r++)                                               \
      __builtin_nontemporal_store(vv[r], (f32x4*)(out + ob + (long)r * NN + l * 4)); \
  }

#define BODY(I, AQ, AK, IP, IT, PAQ, PAK, PIP, PIT) {                          \
    PF((I) + 1, PAQ, PAK, PIP, PIT);                                           \
    CPRED(AQ, IP);                                                             \
    asm volatile("s_waitcnt lgkmcnt(0)" ::: "memory");                         \
    STOREW(0, I);                                                              \
    CTRUE(AK, IT);                                                             \
    asm volatile("s_waitcnt lgkmcnt(0)" ::: "memory");                         \
    STOREW(1, I);                                                              \
  }

  PF(0, aqA, akA, ipA, itA);

#pragma unroll 1
  for (int i2 = 0; i2 < 16; i2++) {
    BODY(2 * i2,     aqA, akA, ipA, itA, aqB, akB, ipB, itB);
    BODY(2 * i2 + 1, aqB, akB, ipB, itB, aqA, akA, ipA, itA);
  }

#undef PF
#undef CPRED
#undef CTRUE
#undef STOREW
#undef BODY
}

extern "C" void kernel_launch(void* const* d_in, const int* in_sizes, int n_in,
                              void* d_out, int out_size, void* d_ws, size_t ws_size,
                              hipStream_t stream) {
  const float* x   = (const float*)d_in[0];
  const float* Wq  = (const float*)d_in[1];
  const float* bq  = (const float*)d_in[2];
  const float* Wk  = (const float*)d_in[3];
  const float* bk  = (const float*)d_in[4];
  const float* Wmq = (const float*)d_in[5];
  const float* bmq = (const float*)d_in[6];
  const float* Wmk = (const float*)d_in[7];
  const float* bmk = (const float*)d_in[8];
  float* out = (float*)d_out;

  // ws layout (bf16): q0[32][2048][64], k0[...], fq[32][2048][128], fk[...] = 48 MB
  unsigned short* q0w = (unsigned short*)d_ws;
  unsigned short* k0w = q0w + (long)NBH * NN * 64;
  unsigned short* fqw = k0w + (long)NBH * NN * 64;
  unsigned short* fkw = fqw + (long)NBH * NN * 128;

  hipLaunchKernelGGL(k_proj, dim3(1024), dim3(256), 0, stream,
                     x, Wq, bq, Wk, bk, Wmq, bmq, Wmk, bmk, q0w, k0w, fqw, fkw);
  hipLaunchKernelGGL(k_colsum1, dim3(NBH, 8), dim3(256), 0, stream, fkw);
  hipLaunchKernelGGL(k_normP, dim3(NBH, 16), dim3(256), 0, stream, fqw);
  hipLaunchKernelGGL(k_normT, dim3(NBH, 64), dim3(256), 0, stream, q0w, k0w);
  hipLaunchKernelGGL(k_write, dim3(NBH, 8), dim3(256), 0, stream,
                     q0w, k0w, fqw, fkw, out);
}